// Round 9
// baseline (916.590 us; speedup 1.0000x reference)
//
#include <hip/hip_runtime.h>
#include <math.h>

#define HDIM 32
#define NHEAD 8
#define DMODEL 256
#define NTYPE 4
#define ETYPE 3
#define NLAYER 3

typedef unsigned short u16;
typedef __bf16 bf16x8 __attribute__((ext_vector_type(8)));
typedef float f32x4 __attribute__((ext_vector_type(4)));

__device__ __forceinline__ u16 f2bf(float f) {
  union { float f; unsigned u; } v; v.f = f;
  unsigned r = v.u + 0x7FFF + ((v.u >> 16) & 1);
  return (u16)(r >> 16);
}

// fast GELU (tanh form)
__device__ __forceinline__ float gelu_f(float v) {
  float u = 0.7978845608028654f * v * (1.f + 0.044715f * v * v);
  float e = __expf(-2.f * fabsf(u));
  float th = (1.f - e) / (1.f + e);
  th = copysignf(th, u);
  return 0.5f * v * (1.f + th);
}

#define GLDS16(g, l)                                              \
  __builtin_amdgcn_global_load_lds(                               \
      (const __attribute__((address_space(1))) void*)(g),         \
      (__attribute__((address_space(3))) void*)(l), 16, 0, 0)

// ---------------------------------------------------------------------------
// CSR build (dst-sorted edge VALUES in position order)
// ---------------------------------------------------------------------------
__global__ void count_deg_kernel(const int* __restrict__ dst, int* __restrict__ deg, int E) {
  int tid = blockIdx.x * 256 + threadIdx.x;
  if (tid < E) atomicAdd(&deg[dst[tid]], 1);
}

__global__ __launch_bounds__(1024) void scan_kernel(const int* __restrict__ deg,
                                                    int* __restrict__ off, int n) {
  __shared__ int part[1024];
  int t = threadIdx.x;
  int chunk = (n + 1023) >> 10;
  int base = t * chunk;
  int s = 0;
  for (int i = 0; i < chunk; ++i) {
    int idx = base + i;
    if (idx < n) s += deg[idx];
  }
  part[t] = s;
  __syncthreads();
  for (int o = 1; o < 1024; o <<= 1) {
    int v = (t >= o) ? part[t - o] : 0;
    __syncthreads();
    part[t] += v;
    __syncthreads();
  }
  int run = part[t] - s;
  for (int i = 0; i < chunk; ++i) {
    int idx = base + i;
    if (idx < n) { off[idx] = run; run += deg[idx]; }
  }
  if (t == 1023) off[n] = part[1023];
}

__global__ void scatter_kernel(const int* __restrict__ src, const int* __restrict__ dst,
                               const int* __restrict__ etype,
                               const int* __restrict__ off, int* __restrict__ cursor,
                               int* __restrict__ csr_src, int* __restrict__ csr_et, int E) {
  int tid = blockIdx.x * 256 + threadIdx.x;
  if (tid < E) {
    int d = dst[tid];
    int p = atomicAdd(&cursor[d], 1);
    int pos = off[d] + p;
    csr_src[pos] = src[tid];
    csr_et[pos] = etype[tid];
  }
}

// ---------------------------------------------------------------------------
// Node-type buckets — hierarchical to avoid same-address atomic contention
// ---------------------------------------------------------------------------
__global__ void tcount_kernel(const int* __restrict__ nt, int* __restrict__ tcnt, int N) {
  __shared__ int h[NTYPE];
  int t = threadIdx.x;
  if (t < NTYPE) h[t] = 0;
  __syncthreads();
  int tid = blockIdx.x * 256 + t;
  if (tid < N) atomicAdd(&h[nt[tid]], 1);
  __syncthreads();
  if (t < NTYPE && h[t] > 0) atomicAdd(&tcnt[t], h[t]);
}

__global__ void tscan_kernel(const int* __restrict__ tcnt, int* __restrict__ toff,
                             int* __restrict__ tile_off) {
  if (threadIdx.x == 0 && blockIdx.x == 0) {
    int o = 0, to = 0;
    for (int t = 0; t < NTYPE; ++t) {
      toff[t] = o; tile_off[t] = to;
      o += tcnt[t]; to += (tcnt[t] + 63) >> 6;
    }
    toff[NTYPE] = o; tile_off[NTYPE] = to;
  }
}

__global__ void tscatter_kernel(const int* __restrict__ nt, const int* __restrict__ toff,
                                int* __restrict__ tcur, int* __restrict__ tidx, int N) {
  int tid = blockIdx.x * 256 + threadIdx.x;
  int lane = threadIdx.x & 63;
  int ty = (tid < N) ? nt[tid] : -1;
  unsigned long long lt_mask = (lane == 63) ? 0x7FFFFFFFFFFFFFFFull
                                            : ((1ull << lane) - 1);
#pragma unroll
  for (int t4 = 0; t4 < NTYPE; ++t4) {
    unsigned long long mask = __ballot(ty == t4);
    if (mask == 0) continue;
    int first = __builtin_ctzll(mask);
    int cnt = __popcll(mask);
    int base = 0;
    if (lane == first) base = atomicAdd(&tcur[t4], cnt);
    base = __shfl(base, first, 64);
    if (ty == t4) {
      int rank = __popcll(mask & lt_mask);
      tidx[toff[t4] + base + rank] = tid;
    }
  }
}

// ---------------------------------------------------------------------------
// x fp32 -> bf16 mirror
// ---------------------------------------------------------------------------
__global__ void xconv_kernel(const float* __restrict__ x, u16* __restrict__ xb, int n4) {
  int i = blockIdx.x * 256 + threadIdx.x;
  if (i < n4) {
    float4 v = ((const float4*)x)[i];
    ushort4 o = { f2bf(v.x), f2bf(v.y), f2bf(v.z), f2bf(v.w) };
    ((ushort4*)xb)[i] = o;
  }
}

// ---------------------------------------------------------------------------
// Weight prep, per (l,type,head): bf16 B-operand mats ([col][k], k contig):
//   mat0 = WK^T (plain K — the gathered operand stays 1x, 10 MB)
//   mat1 = WV^T
//   mat2..4 = WQE[et]: Qe = x @ (WQ @ WE[et]^T) — edge-type transform moved
//            to the dst side (sequential reads), so scores = Qe[dst,et]·K[src]
// ---------------------------------------------------------------------------
__global__ __launch_bounds__(256) void wprep_kernel(
    const float* __restrict__ W_Q, const float* __restrict__ W_K,
    const float* __restrict__ W_V, const float* __restrict__ W_E,
    u16* __restrict__ wqkvb) {
  int b = blockIdx.x;
  int h = b & 7, tt = (b >> 3) & 3, l = b >> 5;
  __shared__ float wq[1024];
  __shared__ float we[3][1024];
  int t = threadIdx.x;
  const float* WQp = W_Q + (((size_t)l * NTYPE + tt) * NHEAD + h) * 1024;
  for (int i = t; i < 1024; i += 256) wq[i] = WQp[i];
  for (int et = 0; et < ETYPE; ++et) {
    const float* WEp = W_E + (((size_t)l * ETYPE + et) * NHEAD + h) * 1024;
    for (int i = t; i < 1024; i += 256) we[et][i] = WEp[i];
  }
  __syncthreads();
  const float* WKp = W_K + (((size_t)l * NTYPE + tt) * NHEAD + h) * 1024;
  const float* WVp = W_V + (((size_t)l * NTYPE + tt) * NHEAD + h) * 1024;
  u16* out = wqkvb + (size_t)b * 5120;
  for (int i = t; i < 1024; i += 256) {
    int col = i >> 5, k = i & 31;   // col = output dim, k = input dim
    out[i] = f2bf(WKp[k * 32 + col]);
    out[1024 + i] = f2bf(WVp[k * 32 + col]);
    // WQE[m=k][d=col] = sum_j WQ[m][j] * WE[et][d][j]
#pragma unroll
    for (int et = 0; et < ETYPE; ++et) {
      float a = 0.f;
#pragma unroll
      for (int j = 0; j < 32; ++j) a += wq[k * 32 + j] * we[et][col * 32 + j];
      out[(2 + et) * 1024 + i] = f2bf(a);
    }
  }
}

// ---------------------------------------------------------------------------
// QKV via MFMA over type buckets: outputs KV (interleaved K|V row, 1 KB/node
// -> single contiguous gather target in sagg) and Qe[3].
// ---------------------------------------------------------------------------
__global__ __launch_bounds__(256) void qkv_mfma(
    const u16* __restrict__ xb, const int* __restrict__ tidx,
    const int* __restrict__ toff, const int* __restrict__ tile_off,
    const u16* __restrict__ wqkvb_l,
    u16* __restrict__ KVb, u16* __restrict__ Qeb) {
  __shared__ u16 smem[10240];
  int bx = blockIdx.x, h = blockIdx.y;
  if (bx >= tile_off[NTYPE]) return;
  int ty = 0;
  while (bx >= tile_off[ty + 1]) ++ty;
  int lt = bx - tile_off[ty];
  int base = toff[ty] + lt * 64;
  int cnt = min(64, toff[ty + 1] - toff[ty] - lt * 64);
  int t = threadIdx.x;
  {
    int row = t >> 2, q = t & 3;
    int node = tidx[base + min(row, cnt - 1)];
    *(uint4*)&smem[row * 32 + q * 8] =
        *(const uint4*)&xb[(size_t)node * 256 + h * 32 + q * 8];
  }
  const u16* wsrc = wqkvb_l + ((size_t)ty * NHEAD + h) * 5120;
  for (int c = t; c < 640; c += 256)
    *(uint4*)&smem[2048 + c * 8] = *(const uint4*)&wsrc[c * 8];
  __syncthreads();

  int lane = t & 63, w = t >> 6;
  int m = lane & 15, q = lane >> 4;
  bf16x8 af = *(const bf16x8*)&smem[(w * 16 + m) * 32 + q * 8];
  f32x4 acc[5][2];
#pragma unroll
  for (int mt = 0; mt < 5; ++mt)
#pragma unroll
    for (int c = 0; c < 2; ++c) {
      bf16x8 bf = *(const bf16x8*)&smem[2048 + mt * 1024 + (c * 16 + m) * 32 + q * 8];
      acc[mt][c] = __builtin_amdgcn_mfma_f32_16x16x32_bf16(af, bf, (f32x4){0.f, 0.f, 0.f, 0.f}, 0, 0, 0);
    }
  __syncthreads();
#pragma unroll
  for (int mt = 0; mt < 5; ++mt)
#pragma unroll
    for (int c = 0; c < 2; ++c)
#pragma unroll
      for (int r = 0; r < 4; ++r)
        smem[mt * 2048 + (w * 16 + q * 4 + r) * 32 + c * 16 + m] = f2bf(acc[mt][c][r]);
  __syncthreads();
  {
    int row = t >> 2, q4 = t & 3;
    if (row < cnt) {
      int node = tidx[base + row];
      // mat0 = K -> KV[node][0:256); mat1 = V -> KV[node][256:512)
      *(uint4*)&KVb[(size_t)node * 512 + h * 32 + q4 * 8] =
          *(const uint4*)&smem[row * 32 + q4 * 8];
      *(uint4*)&KVb[(size_t)node * 512 + 256 + h * 32 + q4 * 8] =
          *(const uint4*)&smem[2048 + row * 32 + q4 * 8];
#pragma unroll
      for (int et = 0; et < ETYPE; ++et)
        *(uint4*)&Qeb[((size_t)node * ETYPE + et) * 256 + h * 32 + q4 * 8] =
            *(const uint4*)&smem[(2 + et) * 2048 + row * 32 + q4 * 8];
    }
  }
}

// ---------------------------------------------------------------------------
// FUSED edge scores + segment softmax + V aggregation. Block per dst node:
// 3 Qe rows read once (sequential); per edge ONE contiguous 1 KB KV[src]
// gather; 8 head-dots via 32-lane shuffle butterfly; exp (no max-sub — LN'd
// inputs, |score|<<88); accumulate e*V and e; normalize at end.
// Replaces score_kernel+agg_kernel: kills the scores array (20 MB r+w), the
// per-edge Q re-reads, and the 30 MB Kt gather working set (now 20 MB KV).
// ---------------------------------------------------------------------------
__global__ __launch_bounds__(256) void sagg_kernel(
    const int* __restrict__ off, const int* __restrict__ csr_src,
    const int* __restrict__ csr_et, const u16* __restrict__ KVb,
    const u16* __restrict__ Qeb, const float* __restrict__ mu,
    u16* __restrict__ aggb) {
  int n = blockIdx.x;
  int t = threadIdx.x;
  int h = t >> 5;
  int s0 = off[n], s1 = off[n + 1];
  float qe[ETYPE], muv[ETYPE];
#pragma unroll
  for (int et = 0; et < ETYPE; ++et) {
    qe[et] = (float)*(const __bf16*)&Qeb[((size_t)n * ETYPE + et) * 256 + t];
    muv[et] = mu[h * ETYPE + et] * 0.17677669529663687f;
  }
  float acc = 0.f, ssum = 0.f;
  int k = s0;
  for (; k + 1 < s1; k += 2) {
    int sn0 = csr_src[k], sn1 = csr_src[k + 1];
    int et0 = csr_et[k], et1 = csr_et[k + 1];
    float k0 = (float)*(const __bf16*)&KVb[(size_t)sn0 * 512 + t];
    float v0 = (float)*(const __bf16*)&KVb[(size_t)sn0 * 512 + 256 + t];
    float k1 = (float)*(const __bf16*)&KVb[(size_t)sn1 * 512 + t];
    float v1 = (float)*(const __bf16*)&KVb[(size_t)sn1 * 512 + 256 + t];
    float p0 = qe[et0] * k0;
    float p1 = qe[et1] * k1;
#pragma unroll
    for (int o = 16; o > 0; o >>= 1) {
      p0 += __shfl_xor(p0, o, 32);
      p1 += __shfl_xor(p1, o, 32);
    }
    float e0 = __expf(p0 * muv[et0]);
    float e1 = __expf(p1 * muv[et1]);
    acc += e0 * v0 + e1 * v1;
    ssum += e0 + e1;
  }
  if (k < s1) {
    int sn0 = csr_src[k];
    int et0 = csr_et[k];
    float k0 = (float)*(const __bf16*)&KVb[(size_t)sn0 * 512 + t];
    float v0 = (float)*(const __bf16*)&KVb[(size_t)sn0 * 512 + 256 + t];
    float p0 = qe[et0] * k0;
#pragma unroll
    for (int o = 16; o > 0; o >>= 1) p0 += __shfl_xor(p0, o, 32);
    float e0 = __expf(p0 * muv[et0]);
    acc += e0 * v0;
    ssum += e0;
  }
  aggb[(size_t)n * 256 + t] = f2bf(acc / (ssum + 1e-10f));
}

// ---------------------------------------------------------------------------
// fp32 [K,Nc] -> bf16 transposed [Nc,K]
// ---------------------------------------------------------------------------
__global__ __launch_bounds__(256) void convT_kernel(const float* __restrict__ W,
                                                    u16* __restrict__ Wt, int K, int Nc) {
  __shared__ float tile[32][33];
  int bk = blockIdx.y * 32, bn = blockIdx.x * 32;
  const float* Wz = W + (size_t)blockIdx.z * K * Nc;
  u16* Wtz = Wt + (size_t)blockIdx.z * K * Nc;
  int tx = threadIdx.x & 31, ty = threadIdx.x >> 5;
  for (int r = ty; r < 32; r += 8)
    tile[r][tx] = Wz[(size_t)(bk + r) * Nc + bn + tx];
  __syncthreads();
  for (int r = ty; r < 32; r += 8)
    Wtz[(size_t)(bn + r) * K + bk + tx] = f2bf(tile[tx][r]);
}

// ---------------------------------------------------------------------------
// bf16 MFMA GEMM (m97 structure): C[M,Nc] = A[M,K] @ Bt[Nc,K]^T + bias.
// BM=128, BN template (64 for Nc=256 outputs to keep the grid >600 blocks).
// ---------------------------------------------------------------------------
template <int EPI, int BN>  // EPI 0: fp32 out + bias; 1: bf16 out + bias + fast GELU
__global__ __launch_bounds__(256) void gemm_mfma(
    const u16* __restrict__ A, const u16* __restrict__ Bt,
    const float* __restrict__ bias, float* __restrict__ Cf,
    u16* __restrict__ Cb, int M, int K, int Nc) {
  __shared__ u16 As[128 * 32];
  __shared__ u16 Bs[BN * 32];
  const int MJ = BN / 32;
  const int t = threadIdx.x;
  const int lane = t & 63;
  const int w = t >> 6;
  const int row0 = blockIdx.y * 128;
  const int col0 = blockIdx.x * BN;
  const int wm = (w >> 1) * 64, wn = (w & 1) * (BN / 2);

  f32x4 acc[4][4] = {};
  const int sr = lane >> 2;
  const int sk = (lane & 3) * 8;

  for (int k0 = 0; k0 < K; k0 += 32) {
#pragma unroll
    for (int c = 0; c < 2; ++c) {
      const int chunk = w * 2 + c;
      const int r = chunk * 16 + sr;
      int ra = row0 + r; if (ra >= M) ra = M - 1;
      GLDS16(A + (size_t)ra * K + k0 + sk, &As[(chunk * 64 + lane) * 8]);
      if (BN == 128) {
        GLDS16(Bt + (size_t)(col0 + r) * K + k0 + sk, &Bs[(chunk * 64 + lane) * 8]);
      }
    }
    if (BN == 64) {
      const int r = w * 16 + sr;
      GLDS16(Bt + (size_t)(col0 + r) * K + k0 + sk, &Bs[(w * 64 + lane) * 8]);
    }
    __syncthreads();
    bf16x8 af[4], bfr[4];
    const int ko = (lane >> 4) * 8;
    const int lr = lane & 15;
#pragma unroll
    for (int i = 0; i < 4; ++i)
      af[i] = *(const bf16x8*)&As[(wm + i * 16 + lr) * 32 + ko];
#pragma unroll
    for (int j = 0; j < MJ; ++j)
      bfr[j] = *(const bf16x8*)&Bs[(wn + j * 16 + lr) * 32 + ko];
#pragma unroll
    for (int i = 0; i < 4; ++i)
#pragma unroll
      for (int j = 0; j < MJ; ++j)
        acc[i][j] = __builtin_amdgcn_mfma_f32_16x16x32_bf16(af[i], bfr[j], acc[i][j], 0, 0, 0);
    __syncthreads();
  }

  const int lc = lane & 15;
  const int lrow = (lane >> 4) * 4;
#pragma unroll
  for (int i = 0; i < 4; ++i) {
#pragma unroll
    for (int r = 0; r < 4; ++r) {
      int gr = row0 + wm + i * 16 + lrow + r;
      if (gr >= M) continue;
#pragma unroll
      for (int j = 0; j < MJ; ++j) {
        int gc = col0 + wn + j * 16 + lc;
        float v = acc[i][j][r] + bias[gc];
        if (EPI == 1) {
          Cb[(size_t)gr * Nc + gc] = f2bf(gelu_f(v));
        } else {
          Cf[(size_t)gr * Nc + gc] = v;
        }
      }
    }
  }
}

// ---------------------------------------------------------------------------
// LayerNorm rows of 256: out = LN(xin + res) * g + b; optional bf16 mirror
// ---------------------------------------------------------------------------
__global__ __launch_bounds__(256) void ln_kernel(
    const float* __restrict__ xin, const float* __restrict__ res,
    const float* __restrict__ g, const float* __restrict__ b,
    float* __restrict__ out, u16* __restrict__ outb) {
  int n = blockIdx.x;
  int t = threadIdx.x;
  __shared__ float red[8];
  size_t idx = (size_t)n * 256 + t;
  float r = xin[idx] + (res ? res[idx] : 0.f);
  float s = r;
  for (int o = 32; o > 0; o >>= 1) s += __shfl_xor(s, o, 64);
  if ((t & 63) == 0) red[t >> 6] = s;
  __syncthreads();
  float m = (red[0] + red[1] + red[2] + red[3]) * (1.f / 256.f);
  float d = r - m;
  float s2 = d * d;
  for (int o = 32; o > 0; o >>= 1) s2 += __shfl_xor(s2, o, 64);
  if ((t & 63) == 0) red[4 + (t >> 6)] = s2;
  __syncthreads();
  float var = (red[4] + red[5] + red[6] + red[7]) * (1.f / 256.f);
  float o = d * rsqrtf(var + 1e-5f) * g[t] + b[t];
  out[idx] = o;
  if (outb) outb[idx] = f2bf(o);
}

// ---------------------------------------------------------------------------
extern "C" void kernel_launch(void* const* d_in, const int* in_sizes, int n_in,
                              void* d_out, int out_size, void* d_ws, size_t ws_size,
                              hipStream_t stream) {
  const float* x_in   = (const float*)d_in[0];
  const int*   ei     = (const int*)d_in[1];
  const int*   etype  = (const int*)d_in[2];
  const int*   ntype  = (const int*)d_in[3];
  const float* W_Q    = (const float*)d_in[4];
  const float* W_K    = (const float*)d_in[5];
  const float* W_V    = (const float*)d_in[6];
  const float* W_E    = (const float*)d_in[7];
  const float* mu     = (const float*)d_in[8];
  const float* Wo     = (const float*)d_in[9];
  const float* bo     = (const float*)d_in[10];
  const float* ln1g   = (const float*)d_in[11];
  const float* ln1b   = (const float*)d_in[12];
  const float* ln2g   = (const float*)d_in[13];
  const float* ln2b   = (const float*)d_in[14];
  const float* w1     = (const float*)d_in[15];
  const float* b1     = (const float*)d_in[16];
  const float* w2     = (const float*)d_in[17];
  const float* b2     = (const float*)d_in[18];
  const float* outg   = (const float*)d_in[19];
  const float* outb   = (const float*)d_in[20];

  const int N = in_sizes[0] / DMODEL;    // 20000
  const int E = in_sizes[1] / 2;         // 320000
  const int* src = ei;
  const int* dst = ei + E;

  const size_t NF = (size_t)N * DMODEL;

  // ---- workspace layout ----
  float* f      = (float*)d_ws;
  float* xbuf   = f;                     // NF fp32
  float* fout   = f + NF;                // NF fp32
  u16*   xb     = (u16*)(f + 2 * NF);    // NF bf16
  u16*   KVb    = xb + NF;               // 2NF (K|V interleaved per node)
  u16*   Qeb    = KVb + 2 * NF;          // 3NF  } h1b aliases Qeb
  u16*   h1b    = Qeb;                   // alias (2NF used)
  u16*   aggb   = Qeb + 3 * NF;          // NF
  u16*   wqkvb  = aggb + NF;             // 96 * 5120
  u16*   Wot    = wqkvb + (size_t)NLAYER * NTYPE * NHEAD * 5120;
  u16*   w1t    = Wot + 3 * 65536;
  u16*   w2t    = w1t + 3 * 262144;
  int*   ip     = (int*)(w2t + 3 * 262144);
  int*   off    = ip;                    // N+1
  int*   csr_src= off + (N + 1);         // E
  int*   csr_et = csr_src + E;           // E
  int*   cursor = csr_et + E;            // N
  int*   tidx   = cursor + N;            // N
  int*   toff   = tidx + N;              // NTYPE+1
  int*   tile_off = toff + (NTYPE + 1);  // NTYPE+1
  int*   tcnt   = tile_off + (NTYPE + 1);// NTYPE
  int*   tcur   = tcnt + NTYPE;          // NTYPE

  // ---- CSR + type buckets (once) ----
  hipMemsetAsync(cursor, 0, (size_t)N * sizeof(int), stream);
  hipMemsetAsync(tcnt, 0, 2 * NTYPE * sizeof(int), stream);
  count_deg_kernel<<<(E + 255) / 256, 256, 0, stream>>>(dst, cursor, E);
  scan_kernel<<<1, 1024, 0, stream>>>(cursor, off, N);
  hipMemsetAsync(cursor, 0, (size_t)N * sizeof(int), stream);
  scatter_kernel<<<(E + 255) / 256, 256, 0, stream>>>(
      src, dst, etype, off, cursor, csr_src, csr_et, E);
  tcount_kernel<<<(N + 255) / 256, 256, 0, stream>>>(ntype, tcnt, N);
  tscan_kernel<<<1, 64, 0, stream>>>(tcnt, toff, tile_off);
  tscatter_kernel<<<(N + 255) / 256, 256, 0, stream>>>(ntype, toff, tcur, tidx, N);

  // ---- weight prep (once) ----
  wprep_kernel<<<NLAYER * NTYPE * NHEAD, 256, 0, stream>>>(W_Q, W_K, W_V, W_E, wqkvb);
  convT_kernel<<<dim3(DMODEL / 32, DMODEL / 32, NLAYER), 256, 0, stream>>>(
      Wo, Wot, DMODEL, DMODEL);
  convT_kernel<<<dim3(4 * DMODEL / 32, DMODEL / 32, NLAYER), 256, 0, stream>>>(
      w1, w1t, DMODEL, 4 * DMODEL);
  convT_kernel<<<dim3(DMODEL / 32, 4 * DMODEL / 32, NLAYER), 256, 0, stream>>>(
      w2, w2t, 4 * DMODEL, DMODEL);

  // ---- x working copies ----
  hipMemcpyAsync(xbuf, x_in, NF * sizeof(float), hipMemcpyDeviceToDevice, stream);
  xconv_kernel<<<(int)((NF / 4 + 255) / 256), 256, 0, stream>>>(x_in, xb, (int)(NF / 4));

  const int gm = (N + 127) / 128;
  const int qtiles = (N + 63) / 64 + NTYPE;
  for (int l = 0; l < NLAYER; ++l) {
    qkv_mfma<<<dim3(qtiles, NHEAD), 256, 0, stream>>>(
        xb, tidx, toff, tile_off,
        wqkvb + (size_t)l * NTYPE * NHEAD * 5120, KVb, Qeb);
    sagg_kernel<<<N, 256, 0, stream>>>(
        off, csr_src, csr_et, KVb, Qeb, mu + (size_t)l * NHEAD * ETYPE, aggb);

    gemm_mfma<0, 64><<<dim3(DMODEL / 64, gm), 256, 0, stream>>>(
        aggb, Wot + (size_t)l * 65536, bo + (size_t)l * DMODEL,
        fout, nullptr, N, DMODEL, DMODEL);
    ln_kernel<<<N, 256, 0, stream>>>(xbuf, fout,
        ln1g + (size_t)l * DMODEL, ln1b + (size_t)l * DMODEL, xbuf, xb);
    gemm_mfma<1, 128><<<dim3(4 * DMODEL / 128, gm), 256, 0, stream>>>(
        xb, w1t + (size_t)l * 262144, b1 + (size_t)l * 4 * DMODEL,
        nullptr, h1b, N, DMODEL, 4 * DMODEL);
    gemm_mfma<0, 64><<<dim3(DMODEL / 64, gm), 256, 0, stream>>>(
        h1b, w2t + (size_t)l * 262144, b2 + (size_t)l * DMODEL,
        fout, nullptr, N, 4 * DMODEL, DMODEL);
    ln_kernel<<<N, 256, 0, stream>>>(xbuf, fout,
        ln2g + (size_t)l * DMODEL, ln2b + (size_t)l * DMODEL, xbuf, xb);
  }

  ln_kernel<<<N, 256, 0, stream>>>(xbuf, nullptr, outg, outb, (float*)d_out, nullptr);
}

// Round 10
// 879.212 us; speedup vs baseline: 1.0425x; 1.0425x over previous
//
#include <hip/hip_runtime.h>
#include <hip/hip_fp8.h>
#include <math.h>

#define HDIM 32
#define NHEAD 8
#define DMODEL 256
#define NTYPE 4
#define ETYPE 3
#define NLAYER 3

typedef unsigned short u16;
typedef unsigned char u8;
typedef __bf16 bf16x8 __attribute__((ext_vector_type(8)));
typedef float f32x4 __attribute__((ext_vector_type(4)));

__device__ __forceinline__ u16 f2bf(float f) {
  union { float f; unsigned u; } v; v.f = f;
  unsigned r = v.u + 0x7FFF + ((v.u >> 16) & 1);
  return (u16)(r >> 16);
}
__device__ __forceinline__ float bf2f(u16 b) {
  union { unsigned u; float f; } v; v.u = (unsigned)b << 16; return v.f;
}
__device__ __forceinline__ u8 f2fp8(float v) {
  __hip_fp8_e4m3 t(v); return (u8)t.__x;
}
__device__ __forceinline__ float fp82f(unsigned b) {
  __hip_fp8_e4m3 t; t.__x = (__hip_fp8_storage_t)b; return (float)t;
}

// fast GELU (tanh form)
__device__ __forceinline__ float gelu_f(float v) {
  float u = 0.7978845608028654f * v * (1.f + 0.044715f * v * v);
  float e = __expf(-2.f * fabsf(u));
  float th = (1.f - e) / (1.f + e);
  th = copysignf(th, u);
  return 0.5f * v * (1.f + th);
}

#define GLDS16(g, l)                                              \
  __builtin_amdgcn_global_load_lds(                               \
      (const __attribute__((address_space(1))) void*)(g),         \
      (__attribute__((address_space(3))) void*)(l), 16, 0, 0)

// ---------------------------------------------------------------------------
// CSR build (dst-sorted edge VALUES in position order)
// ---------------------------------------------------------------------------
__global__ void count_deg_kernel(const int* __restrict__ dst, int* __restrict__ deg, int E) {
  int tid = blockIdx.x * 256 + threadIdx.x;
  if (tid < E) atomicAdd(&deg[dst[tid]], 1);
}

__global__ __launch_bounds__(1024) void scan_kernel(const int* __restrict__ deg,
                                                    int* __restrict__ off, int n) {
  __shared__ int part[1024];
  int t = threadIdx.x;
  int chunk = (n + 1023) >> 10;
  int base = t * chunk;
  int s = 0;
  for (int i = 0; i < chunk; ++i) {
    int idx = base + i;
    if (idx < n) s += deg[idx];
  }
  part[t] = s;
  __syncthreads();
  for (int o = 1; o < 1024; o <<= 1) {
    int v = (t >= o) ? part[t - o] : 0;
    __syncthreads();
    part[t] += v;
    __syncthreads();
  }
  int run = part[t] - s;
  for (int i = 0; i < chunk; ++i) {
    int idx = base + i;
    if (idx < n) { off[idx] = run; run += deg[idx]; }
  }
  if (t == 1023) off[n] = part[1023];
}

__global__ void scatter_kernel(const int* __restrict__ src, const int* __restrict__ dst,
                               const int* __restrict__ etype,
                               const int* __restrict__ off, int* __restrict__ cursor,
                               int* __restrict__ csr_src, int* __restrict__ csr_dst,
                               int* __restrict__ csr_et, int E) {
  int tid = blockIdx.x * 256 + threadIdx.x;
  if (tid < E) {
    int d = dst[tid];
    int p = atomicAdd(&cursor[d], 1);
    int pos = off[d] + p;
    csr_src[pos] = src[tid];
    csr_dst[pos] = d;
    csr_et[pos] = etype[tid];
  }
}

// ---------------------------------------------------------------------------
// Node-type buckets — hierarchical to avoid same-address atomic contention
// ---------------------------------------------------------------------------
__global__ void tcount_kernel(const int* __restrict__ nt, int* __restrict__ tcnt, int N) {
  __shared__ int h[NTYPE];
  int t = threadIdx.x;
  if (t < NTYPE) h[t] = 0;
  __syncthreads();
  int tid = blockIdx.x * 256 + t;
  if (tid < N) atomicAdd(&h[nt[tid]], 1);
  __syncthreads();
  if (t < NTYPE && h[t] > 0) atomicAdd(&tcnt[t], h[t]);
}

__global__ void tscan_kernel(const int* __restrict__ tcnt, int* __restrict__ toff,
                             int* __restrict__ tile_off) {
  if (threadIdx.x == 0 && blockIdx.x == 0) {
    int o = 0, to = 0;
    for (int t = 0; t < NTYPE; ++t) {
      toff[t] = o; tile_off[t] = to;
      o += tcnt[t]; to += (tcnt[t] + 63) >> 6;
    }
    toff[NTYPE] = o; tile_off[NTYPE] = to;
  }
}

__global__ void tscatter_kernel(const int* __restrict__ nt, const int* __restrict__ toff,
                                int* __restrict__ tcur, int* __restrict__ tidx, int N) {
  int tid = blockIdx.x * 256 + threadIdx.x;
  int lane = threadIdx.x & 63;
  int ty = (tid < N) ? nt[tid] : -1;
  unsigned long long lt_mask = (lane == 63) ? 0x7FFFFFFFFFFFFFFFull
                                            : ((1ull << lane) - 1);
#pragma unroll
  for (int t4 = 0; t4 < NTYPE; ++t4) {
    unsigned long long mask = __ballot(ty == t4);
    if (mask == 0) continue;
    int first = __builtin_ctzll(mask);
    int cnt = __popcll(mask);
    int base = 0;
    if (lane == first) base = atomicAdd(&tcur[t4], cnt);
    base = __shfl(base, first, 64);
    if (ty == t4) {
      int rank = __popcll(mask & lt_mask);
      tidx[toff[t4] + base + rank] = tid;
    }
  }
}

// ---------------------------------------------------------------------------
// x fp32 -> bf16 mirror
// ---------------------------------------------------------------------------
__global__ void xconv_kernel(const float* __restrict__ x, u16* __restrict__ xb, int n4) {
  int i = blockIdx.x * 256 + threadIdx.x;
  if (i < n4) {
    float4 v = ((const float4*)x)[i];
    ushort4 o = { f2bf(v.x), f2bf(v.y), f2bf(v.z), f2bf(v.w) };
    ((ushort4*)xb)[i] = o;
  }
}

// ---------------------------------------------------------------------------
// Weight prep, per (l,type,head): bf16 B-operand mats ([col][k], k contig):
//   mat0 = WK^T, mat1 = WV^T,
//   mat2..4 = WQE[et] with Qe = x @ (WQ @ WE[et]^T)  (edge-type transform on
//   the dst side so the gathered operand is plain K)
// ---------------------------------------------------------------------------
__global__ __launch_bounds__(256) void wprep_kernel(
    const float* __restrict__ W_Q, const float* __restrict__ W_K,
    const float* __restrict__ W_V, const float* __restrict__ W_E,
    u16* __restrict__ wqkvb) {
  int b = blockIdx.x;
  int h = b & 7, tt = (b >> 3) & 3, l = b >> 5;
  __shared__ float wq[1024];
  __shared__ float we[3][1024];
  int t = threadIdx.x;
  const float* WQp = W_Q + (((size_t)l * NTYPE + tt) * NHEAD + h) * 1024;
  for (int i = t; i < 1024; i += 256) wq[i] = WQp[i];
  for (int et = 0; et < ETYPE; ++et) {
    const float* WEp = W_E + (((size_t)l * ETYPE + et) * NHEAD + h) * 1024;
    for (int i = t; i < 1024; i += 256) we[et][i] = WEp[i];
  }
  __syncthreads();
  const float* WKp = W_K + (((size_t)l * NTYPE + tt) * NHEAD + h) * 1024;
  const float* WVp = W_V + (((size_t)l * NTYPE + tt) * NHEAD + h) * 1024;
  u16* out = wqkvb + (size_t)b * 5120;
  for (int i = t; i < 1024; i += 256) {
    int col = i >> 5, k = i & 31;
    out[i] = f2bf(WKp[k * 32 + col]);
    out[1024 + i] = f2bf(WVp[k * 32 + col]);
#pragma unroll
    for (int et = 0; et < ETYPE; ++et) {
      float a = 0.f;
#pragma unroll
      for (int j = 0; j < 32; ++j) a += wq[k * 32 + j] * we[et][col * 32 + j];
      out[(2 + et) * 1024 + i] = f2bf(a);
    }
  }
}

// ---------------------------------------------------------------------------
// QKV via MFMA over type buckets: K,V stored fp8 e4m3 (the randomly-gathered
// arrays — 5 MB each, near-L2-resident; values ~0.11 sit in e4m3 normal
// range); Qe[3] stored bf16 (sequentially read).
// ---------------------------------------------------------------------------
__global__ __launch_bounds__(256) void qkv_mfma(
    const u16* __restrict__ xb, const int* __restrict__ tidx,
    const int* __restrict__ toff, const int* __restrict__ tile_off,
    const u16* __restrict__ wqkvb_l,
    u8* __restrict__ Kb8, u8* __restrict__ Vb8, u16* __restrict__ Qeb) {
  __shared__ u16 smem[10240];
  int bx = blockIdx.x, h = blockIdx.y;
  if (bx >= tile_off[NTYPE]) return;
  int ty = 0;
  while (bx >= tile_off[ty + 1]) ++ty;
  int lt = bx - tile_off[ty];
  int base = toff[ty] + lt * 64;
  int cnt = min(64, toff[ty + 1] - toff[ty] - lt * 64);
  int t = threadIdx.x;
  {
    int row = t >> 2, q = t & 3;
    int node = tidx[base + min(row, cnt - 1)];
    *(uint4*)&smem[row * 32 + q * 8] =
        *(const uint4*)&xb[(size_t)node * 256 + h * 32 + q * 8];
  }
  const u16* wsrc = wqkvb_l + ((size_t)ty * NHEAD + h) * 5120;
  for (int c = t; c < 640; c += 256)
    *(uint4*)&smem[2048 + c * 8] = *(const uint4*)&wsrc[c * 8];
  __syncthreads();

  int lane = t & 63, w = t >> 6;
  int m = lane & 15, q = lane >> 4;
  bf16x8 af = *(const bf16x8*)&smem[(w * 16 + m) * 32 + q * 8];
  f32x4 acc[5][2];
#pragma unroll
  for (int mt = 0; mt < 5; ++mt)
#pragma unroll
    for (int c = 0; c < 2; ++c) {
      bf16x8 bf = *(const bf16x8*)&smem[2048 + mt * 1024 + (c * 16 + m) * 32 + q * 8];
      acc[mt][c] = __builtin_amdgcn_mfma_f32_16x16x32_bf16(af, bf, (f32x4){0.f, 0.f, 0.f, 0.f}, 0, 0, 0);
    }
  __syncthreads();
#pragma unroll
  for (int mt = 0; mt < 5; ++mt)
#pragma unroll
    for (int c = 0; c < 2; ++c)
#pragma unroll
      for (int r = 0; r < 4; ++r)
        smem[mt * 2048 + (w * 16 + q * 4 + r) * 32 + c * 16 + m] = f2bf(acc[mt][c][r]);
  __syncthreads();
  {
    int row = t >> 2, q4 = t & 3;
    if (row < cnt) {
      int node = tidx[base + row];
      // K -> fp8
      {
        const u16* sp = &smem[row * 32 + q4 * 8];
        unsigned long long pk = 0;
#pragma unroll
        for (int j = 0; j < 8; ++j)
          pk |= (unsigned long long)f2fp8(bf2f(sp[j])) << (8 * j);
        *(unsigned long long*)&Kb8[(size_t)node * 256 + h * 32 + q4 * 8] = pk;
      }
      // V -> fp8
      {
        const u16* sp = &smem[2048 + row * 32 + q4 * 8];
        unsigned long long pk = 0;
#pragma unroll
        for (int j = 0; j < 8; ++j)
          pk |= (unsigned long long)f2fp8(bf2f(sp[j])) << (8 * j);
        *(unsigned long long*)&Vb8[(size_t)node * 256 + h * 32 + q4 * 8] = pk;
      }
#pragma unroll
      for (int et = 0; et < ETYPE; ++et)
        *(uint4*)&Qeb[((size_t)node * ETYPE + et) * 256 + h * 32 + q4 * 8] =
            *(const uint4*)&smem[(2 + et) * 2048 + row * 32 + q4 * 8];
    }
  }
}

// ---------------------------------------------------------------------------
// Edge scores -> exp(score). Per (edge,head) thread; gathers a 32 B fp8 K
// segment (K array 5 MB vs R8's 30 MB Kt — the working-set shrink) and reads
// Qe[dst,et] sequentially. No max-sub (|score| << 88, LN'd inputs).
// ---------------------------------------------------------------------------
__global__ __launch_bounds__(256) void score_kernel(
    const int* __restrict__ csr_src, const int* __restrict__ csr_dst,
    const int* __restrict__ csr_et, const u16* __restrict__ Qeb,
    const u8* __restrict__ Kb8, const float* __restrict__ mu,
    float* __restrict__ scores, int E) {
  int tid = blockIdx.x * 256 + threadIdx.x;
  if (tid >= E * NHEAD) return;
  int p = tid >> 3, h = tid & 7;
  int s = csr_src[p], d = csr_dst[p], t = csr_et[p];
  const bf16x8* q = (const bf16x8*)(Qeb + ((size_t)d * ETYPE + t) * 256 + h * 32);
  const uint2* k = (const uint2*)(Kb8 + (size_t)s * 256 + h * 32);
  float acc = 0.f;
#pragma unroll
  for (int g = 0; g < 4; ++g) {
    uint2 kd = k[g];
    bf16x8 qq = q[g];
#pragma unroll
    for (int b = 0; b < 4; ++b) {
      acc += fp82f((kd.x >> (8 * b)) & 0xffu) * (float)qq[b];
      acc += fp82f((kd.y >> (8 * b)) & 0xffu) * (float)qq[4 + b];
    }
  }
  scores[tid] = __expf(acc * 0.17677669529663687f * mu[h * ETYPE + t]);
}

// ---------------------------------------------------------------------------
// Single-pass segment softmax + V aggregation: scores hold exp(s); fp8 V
// gather (5 MB array, 256 B/row) halves the R8 gather bytes.
// ---------------------------------------------------------------------------
__global__ __launch_bounds__(256) void agg_kernel(
    const int* __restrict__ off, const int* __restrict__ csr_src,
    const float* __restrict__ scores, const u8* __restrict__ Vb8,
    u16* __restrict__ aggb) {
  int n = blockIdx.x;
  int t = threadIdx.x;
  int h = t >> 5;
  int s0 = off[n], s1 = off[n + 1];
  const u8* vbase = Vb8 + t;
  float acc = 0.f, ssum = 0.f;
  int k = s0;
  for (; k + 1 < s1; k += 2) {
    float e0 = scores[(size_t)k * 8 + h];
    float e1 = scores[(size_t)(k + 1) * 8 + h];
    int sn0 = csr_src[k], sn1 = csr_src[k + 1];
    float v0 = fp82f(vbase[(size_t)sn0 * 256]);
    float v1 = fp82f(vbase[(size_t)sn1 * 256]);
    acc += e0 * v0 + e1 * v1;
    ssum += e0 + e1;
  }
  if (k < s1) {
    float e0 = scores[(size_t)k * 8 + h];
    int sn0 = csr_src[k];
    acc += e0 * fp82f(vbase[(size_t)sn0 * 256]);
    ssum += e0;
  }
  aggb[(size_t)n * 256 + t] = f2bf(acc / (ssum + 1e-10f));
}

// ---------------------------------------------------------------------------
// fp32 [K,Nc] -> bf16 transposed [Nc,K]
// ---------------------------------------------------------------------------
__global__ __launch_bounds__(256) void convT_kernel(const float* __restrict__ W,
                                                    u16* __restrict__ Wt, int K, int Nc) {
  __shared__ float tile[32][33];
  int bk = blockIdx.y * 32, bn = blockIdx.x * 32;
  const float* Wz = W + (size_t)blockIdx.z * K * Nc;
  u16* Wtz = Wt + (size_t)blockIdx.z * K * Nc;
  int tx = threadIdx.x & 31, ty = threadIdx.x >> 5;
  for (int r = ty; r < 32; r += 8)
    tile[r][tx] = Wz[(size_t)(bk + r) * Nc + bn + tx];
  __syncthreads();
  for (int r = ty; r < 32; r += 8)
    Wtz[(size_t)(bn + r) * K + bk + tx] = f2bf(tile[tx][r]);
}

// ---------------------------------------------------------------------------
// bf16 MFMA GEMM (m97 structure): C[M,Nc] = A[M,K] @ Bt[Nc,K]^T + bias.
// BM=128, BN template (64 for Nc=256 outputs to keep the grid >600 blocks).
// ---------------------------------------------------------------------------
template <int EPI, int BN>  // EPI 0: fp32 out + bias; 1: bf16 out + bias + fast GELU
__global__ __launch_bounds__(256) void gemm_mfma(
    const u16* __restrict__ A, const u16* __restrict__ Bt,
    const float* __restrict__ bias, float* __restrict__ Cf,
    u16* __restrict__ Cb, int M, int K, int Nc) {
  __shared__ u16 As[128 * 32];
  __shared__ u16 Bs[BN * 32];
  const int MJ = BN / 32;
  const int t = threadIdx.x;
  const int lane = t & 63;
  const int w = t >> 6;
  const int row0 = blockIdx.y * 128;
  const int col0 = blockIdx.x * BN;
  const int wm = (w >> 1) * 64, wn = (w & 1) * (BN / 2);

  f32x4 acc[4][4] = {};
  const int sr = lane >> 2;
  const int sk = (lane & 3) * 8;

  for (int k0 = 0; k0 < K; k0 += 32) {
#pragma unroll
    for (int c = 0; c < 2; ++c) {
      const int chunk = w * 2 + c;
      const int r = chunk * 16 + sr;
      int ra = row0 + r; if (ra >= M) ra = M - 1;
      GLDS16(A + (size_t)ra * K + k0 + sk, &As[(chunk * 64 + lane) * 8]);
      if (BN == 128) {
        GLDS16(Bt + (size_t)(col0 + r) * K + k0 + sk, &Bs[(chunk * 64 + lane) * 8]);
      }
    }
    if (BN == 64) {
      const int r = w * 16 + sr;
      GLDS16(Bt + (size_t)(col0 + r) * K + k0 + sk, &Bs[(w * 64 + lane) * 8]);
    }
    __syncthreads();
    bf16x8 af[4], bfr[4];
    const int ko = (lane >> 4) * 8;
    const int lr = lane & 15;
#pragma unroll
    for (int i = 0; i < 4; ++i)
      af[i] = *(const bf16x8*)&As[(wm + i * 16 + lr) * 32 + ko];
#pragma unroll
    for (int j = 0; j < MJ; ++j)
      bfr[j] = *(const bf16x8*)&Bs[(wn + j * 16 + lr) * 32 + ko];
#pragma unroll
    for (int i = 0; i < 4; ++i)
#pragma unroll
      for (int j = 0; j < MJ; ++j)
        acc[i][j] = __builtin_amdgcn_mfma_f32_16x16x32_bf16(af[i], bfr[j], acc[i][j], 0, 0, 0);
    __syncthreads();
  }

  const int lc = lane & 15;
  const int lrow = (lane >> 4) * 4;
#pragma unroll
  for (int i = 0; i < 4; ++i) {
#pragma unroll
    for (int r = 0; r < 4; ++r) {
      int gr = row0 + wm + i * 16 + lrow + r;
      if (gr >= M) continue;
#pragma unroll
      for (int j = 0; j < MJ; ++j) {
        int gc = col0 + wn + j * 16 + lc;
        float v = acc[i][j][r] + bias[gc];
        if (EPI == 1) {
          Cb[(size_t)gr * Nc + gc] = f2bf(gelu_f(v));
        } else {
          Cf[(size_t)gr * Nc + gc] = v;
        }
      }
    }
  }
}

// ---------------------------------------------------------------------------
// LayerNorm rows of 256: out = LN(xin + res) * g + b; optional bf16 mirror
// ---------------------------------------------------------------------------
__global__ __launch_bounds__(256) void ln_kernel(
    const float* __restrict__ xin, const float* __restrict__ res,
    const float* __restrict__ g, const float* __restrict__ b,
    float* __restrict__ out, u16* __restrict__ outb) {
  int n = blockIdx.x;
  int t = threadIdx.x;
  __shared__ float red[8];
  size_t idx = (size_t)n * 256 + t;
  float r = xin[idx] + (res ? res[idx] : 0.f);
  float s = r;
  for (int o = 32; o > 0; o >>= 1) s += __shfl_xor(s, o, 64);
  if ((t & 63) == 0) red[t >> 6] = s;
  __syncthreads();
  float m = (red[0] + red[1] + red[2] + red[3]) * (1.f / 256.f);
  float d = r - m;
  float s2 = d * d;
  for (int o = 32; o > 0; o >>= 1) s2 += __shfl_xor(s2, o, 64);
  if ((t & 63) == 0) red[4 + (t >> 6)] = s2;
  __syncthreads();
  float var = (red[4] + red[5] + red[6] + red[7]) * (1.f / 256.f);
  float o = d * rsqrtf(var + 1e-5f) * g[t] + b[t];
  out[idx] = o;
  if (outb) outb[idx] = f2bf(o);
}

// ---------------------------------------------------------------------------
extern "C" void kernel_launch(void* const* d_in, const int* in_sizes, int n_in,
                              void* d_out, int out_size, void* d_ws, size_t ws_size,
                              hipStream_t stream) {
  const float* x_in   = (const float*)d_in[0];
  const int*   ei     = (const int*)d_in[1];
  const int*   etype  = (const int*)d_in[2];
  const int*   ntype  = (const int*)d_in[3];
  const float* W_Q    = (const float*)d_in[4];
  const float* W_K    = (const float*)d_in[5];
  const float* W_V    = (const float*)d_in[6];
  const float* W_E    = (const float*)d_in[7];
  const float* mu     = (const float*)d_in[8];
  const float* Wo     = (const float*)d_in[9];
  const float* bo     = (const float*)d_in[10];
  const float* ln1g   = (const float*)d_in[11];
  const float* ln1b   = (const float*)d_in[12];
  const float* ln2g   = (const float*)d_in[13];
  const float* ln2b   = (const float*)d_in[14];
  const float* w1     = (const float*)d_in[15];
  const float* b1     = (const float*)d_in[16];
  const float* w2     = (const float*)d_in[17];
  const float* b2     = (const float*)d_in[18];
  const float* outg   = (const float*)d_in[19];
  const float* outb   = (const float*)d_in[20];

  const int N = in_sizes[0] / DMODEL;    // 20000
  const int E = in_sizes[1] / 2;         // 320000
  const int* src = ei;
  const int* dst = ei + E;

  const size_t NF = (size_t)N * DMODEL;
  const size_t EH = (size_t)E * NHEAD;

  // ---- workspace layout ----
  float* f      = (float*)d_ws;
  float* xbuf   = f;                     // NF fp32
  float* fout   = f + NF;                // NF fp32
  float* scores = f + 2 * NF;            // EH fp32 (holds exp(score))
  u16*   xb     = (u16*)(f + 2 * NF + EH); // NF bf16
  u16*   Qeb    = xb + NF;               // 3NF bf16  } h1b aliases Qeb
  u16*   h1b    = Qeb;                   // alias (2NF used, FFN phase only)
  u16*   aggb   = Qeb + 3 * NF;          // NF bf16
  u8*    Kb8    = (u8*)(aggb + NF);      // NF bytes fp8
  u8*    Vb8    = Kb8 + NF;              // NF bytes fp8
  u16*   wqkvb  = (u16*)(Vb8 + NF);      // 96 * 5120
  u16*   Wot    = wqkvb + (size_t)NLAYER * NTYPE * NHEAD * 5120;
  u16*   w1t    = Wot + 3 * 65536;
  u16*   w2t    = w1t + 3 * 262144;
  int*   ip     = (int*)(w2t + 3 * 262144);
  int*   off    = ip;                    // N+1
  int*   csr_src= off + (N + 1);         // E
  int*   csr_dst= csr_src + E;           // E
  int*   csr_et = csr_dst + E;           // E
  int*   cursor = csr_et + E;            // N
  int*   tidx   = cursor + N;            // N
  int*   toff   = tidx + N;              // NTYPE+1
  int*   tile_off = toff + (NTYPE + 1);  // NTYPE+1
  int*   tcnt   = tile_off + (NTYPE + 1);// NTYPE
  int*   tcur   = tcnt + NTYPE;          // NTYPE

  // ---- CSR + type buckets (once) ----
  hipMemsetAsync(cursor, 0, (size_t)N * sizeof(int), stream);
  hipMemsetAsync(tcnt, 0, 2 * NTYPE * sizeof(int), stream);
  count_deg_kernel<<<(E + 255) / 256, 256, 0, stream>>>(dst, cursor, E);
  scan_kernel<<<1, 1024, 0, stream>>>(cursor, off, N);
  hipMemsetAsync(cursor, 0, (size_t)N * sizeof(int), stream);
  scatter_kernel<<<(E + 255) / 256, 256, 0, stream>>>(
      src, dst, etype, off, cursor, csr_src, csr_dst, csr_et, E);
  tcount_kernel<<<(N + 255) / 256, 256, 0, stream>>>(ntype, tcnt, N);
  tscan_kernel<<<1, 64, 0, stream>>>(tcnt, toff, tile_off);
  tscatter_kernel<<<(N + 255) / 256, 256, 0, stream>>>(ntype, toff, tcur, tidx, N);

  // ---- weight prep (once) ----
  wprep_kernel<<<NLAYER * NTYPE * NHEAD, 256, 0, stream>>>(W_Q, W_K, W_V, W_E, wqkvb);
  convT_kernel<<<dim3(DMODEL / 32, DMODEL / 32, NLAYER), 256, 0, stream>>>(
      Wo, Wot, DMODEL, DMODEL);
  convT_kernel<<<dim3(4 * DMODEL / 32, DMODEL / 32, NLAYER), 256, 0, stream>>>(
      w1, w1t, DMODEL, 4 * DMODEL);
  convT_kernel<<<dim3(DMODEL / 32, 4 * DMODEL / 32, NLAYER), 256, 0, stream>>>(
      w2, w2t, 4 * DMODEL, DMODEL);

  // ---- x working copies ----
  hipMemcpyAsync(xbuf, x_in, NF * sizeof(float), hipMemcpyDeviceToDevice, stream);
  xconv_kernel<<<(int)((NF / 4 + 255) / 256), 256, 0, stream>>>(x_in, xb, (int)(NF / 4));

  const int gm = (N + 127) / 128;
  const int qtiles = (N + 63) / 64 + NTYPE;
  for (int l = 0; l < NLAYER; ++l) {
    qkv_mfma<<<dim3(qtiles, NHEAD), 256, 0, stream>>>(
        xb, tidx, toff, tile_off,
        wqkvb + (size_t)l * NTYPE * NHEAD * 5120, Kb8, Vb8, Qeb);
    score_kernel<<<(int)((EH + 255) / 256), 256, 0, stream>>>(
        csr_src, csr_dst, csr_et, Qeb, Kb8, mu + (size_t)l * NHEAD * ETYPE, scores, E);
    agg_kernel<<<N, 256, 0, stream>>>(off, csr_src, scores, Vb8, aggb);

    gemm_mfma<0, 64><<<dim3(DMODEL / 64, gm), 256, 0, stream>>>(
        aggb, Wot + (size_t)l * 65536, bo + (size_t)l * DMODEL,
        fout, nullptr, N, DMODEL, DMODEL);
    ln_kernel<<<N, 256, 0, stream>>>(xbuf, fout,
        ln1g + (size_t)l * DMODEL, ln1b + (size_t)l * DMODEL, xbuf, xb);
    gemm_mfma<1, 128><<<dim3(4 * DMODEL / 128, gm), 256, 0, stream>>>(
        xb, w1t + (size_t)l * 262144, b1 + (size_t)l * 4 * DMODEL,
        nullptr, h1b, N, DMODEL, 4 * DMODEL);
    gemm_mfma<0, 64><<<dim3(DMODEL / 64, gm), 256, 0, stream>>>(
        h1b, w2t + (size_t)l * 262144, b2 + (size_t)l * DMODEL,
        fout, nullptr, N, 4 * DMODEL, DMODEL);
    ln_kernel<<<N, 256, 0, stream>>>(xbuf, fout,
        ln2g + (size_t)l * DMODEL, ln2b + (size_t)l * DMODEL, xbuf, xb);
  }

  ln_kernel<<<N, 256, 0, stream>>>(xbuf, nullptr, outg, outb, (float*)d_out, nullptr);
}

// Round 11
// 851.787 us; speedup vs baseline: 1.0761x; 1.0322x over previous
//
#include <hip/hip_runtime.h>
#include <hip/hip_fp8.h>
#include <math.h>

#define HDIM 32
#define NHEAD 8
#define DMODEL 256
#define NTYPE 4
#define ETYPE 3
#define NLAYER 3

typedef unsigned short u16;
typedef unsigned char u8;
typedef __bf16 bf16x8 __attribute__((ext_vector_type(8)));
typedef float f32x4 __attribute__((ext_vector_type(4)));

__device__ __forceinline__ u16 f2bf(float f) {
  union { float f; unsigned u; } v; v.f = f;
  unsigned r = v.u + 0x7FFF + ((v.u >> 16) & 1);
  return (u16)(r >> 16);
}
__device__ __forceinline__ float bf2f(u16 b) {
  union { unsigned u; float f; } v; v.u = (unsigned)b << 16; return v.f;
}
__device__ __forceinline__ u8 f2fp8(float v) {
  __hip_fp8_e4m3 t(v); return (u8)t.__x;
}
__device__ __forceinline__ float fp82f(unsigned b) {
  __hip_fp8_e4m3 t; t.__x = (__hip_fp8_storage_t)b; return (float)t;
}

// fast GELU (tanh form)
__device__ __forceinline__ float gelu_f(float v) {
  float u = 0.7978845608028654f * v * (1.f + 0.044715f * v * v);
  float e = __expf(-2.f * fabsf(u));
  float th = (1.f - e) / (1.f + e);
  th = copysignf(th, u);
  return 0.5f * v * (1.f + th);
}

#define GLDS16(g, l)                                              \
  __builtin_amdgcn_global_load_lds(                               \
      (const __attribute__((address_space(1))) void*)(g),         \
      (__attribute__((address_space(3))) void*)(l), 16, 0, 0)

// ---------------------------------------------------------------------------
// CSR build (dst-sorted edge VALUES in position order)
// ---------------------------------------------------------------------------
__global__ void count_deg_kernel(const int* __restrict__ dst, int* __restrict__ deg, int E) {
  int tid = blockIdx.x * 256 + threadIdx.x;
  if (tid < E) atomicAdd(&deg[dst[tid]], 1);
}

__global__ __launch_bounds__(1024) void scan_kernel(const int* __restrict__ deg,
                                                    int* __restrict__ off, int n) {
  __shared__ int part[1024];
  int t = threadIdx.x;
  int chunk = (n + 1023) >> 10;
  int base = t * chunk;
  int s = 0;
  for (int i = 0; i < chunk; ++i) {
    int idx = base + i;
    if (idx < n) s += deg[idx];
  }
  part[t] = s;
  __syncthreads();
  for (int o = 1; o < 1024; o <<= 1) {
    int v = (t >= o) ? part[t - o] : 0;
    __syncthreads();
    part[t] += v;
    __syncthreads();
  }
  int run = part[t] - s;
  for (int i = 0; i < chunk; ++i) {
    int idx = base + i;
    if (idx < n) { off[idx] = run; run += deg[idx]; }
  }
  if (t == 1023) off[n] = part[1023];
}

__global__ void scatter_kernel(const int* __restrict__ src, const int* __restrict__ dst,
                               const int* __restrict__ etype,
                               const int* __restrict__ off, int* __restrict__ cursor,
                               int* __restrict__ csr_src, int* __restrict__ csr_dst,
                               int* __restrict__ csr_et, int E) {
  int tid = blockIdx.x * 256 + threadIdx.x;
  if (tid < E) {
    int d = dst[tid];
    int p = atomicAdd(&cursor[d], 1);
    int pos = off[d] + p;
    csr_src[pos] = src[tid];
    csr_dst[pos] = d;
    csr_et[pos] = etype[tid];
  }
}

// ---------------------------------------------------------------------------
// Node-type buckets — hierarchical to avoid same-address atomic contention
// ---------------------------------------------------------------------------
__global__ void tcount_kernel(const int* __restrict__ nt, int* __restrict__ tcnt, int N) {
  __shared__ int h[NTYPE];
  int t = threadIdx.x;
  if (t < NTYPE) h[t] = 0;
  __syncthreads();
  int tid = blockIdx.x * 256 + t;
  if (tid < N) atomicAdd(&h[nt[tid]], 1);
  __syncthreads();
  if (t < NTYPE && h[t] > 0) atomicAdd(&tcnt[t], h[t]);
}

__global__ void tscan_kernel(const int* __restrict__ tcnt, int* __restrict__ toff,
                             int* __restrict__ tile_off) {
  if (threadIdx.x == 0 && blockIdx.x == 0) {
    int o = 0, to = 0;
    for (int t = 0; t < NTYPE; ++t) {
      toff[t] = o; tile_off[t] = to;
      o += tcnt[t]; to += (tcnt[t] + 63) >> 6;
    }
    toff[NTYPE] = o; tile_off[NTYPE] = to;
  }
}

__global__ void tscatter_kernel(const int* __restrict__ nt, const int* __restrict__ toff,
                                int* __restrict__ tcur, int* __restrict__ tidx, int N) {
  int tid = blockIdx.x * 256 + threadIdx.x;
  int lane = threadIdx.x & 63;
  int ty = (tid < N) ? nt[tid] : -1;
  unsigned long long lt_mask = (lane == 63) ? 0x7FFFFFFFFFFFFFFFull
                                            : ((1ull << lane) - 1);
#pragma unroll
  for (int t4 = 0; t4 < NTYPE; ++t4) {
    unsigned long long mask = __ballot(ty == t4);
    if (mask == 0) continue;
    int first = __builtin_ctzll(mask);
    int cnt = __popcll(mask);
    int base = 0;
    if (lane == first) base = atomicAdd(&tcur[t4], cnt);
    base = __shfl(base, first, 64);
    if (ty == t4) {
      int rank = __popcll(mask & lt_mask);
      tidx[toff[t4] + base + rank] = tid;
    }
  }
}

// ---------------------------------------------------------------------------
// x fp32 -> bf16 mirror
// ---------------------------------------------------------------------------
__global__ void xconv_kernel(const float* __restrict__ x, u16* __restrict__ xb, int n4) {
  int i = blockIdx.x * 256 + threadIdx.x;
  if (i < n4) {
    float4 v = ((const float4*)x)[i];
    ushort4 o = { f2bf(v.x), f2bf(v.y), f2bf(v.z), f2bf(v.w) };
    ((ushort4*)xb)[i] = o;
  }
}

// ---------------------------------------------------------------------------
// Weight prep, per (l,type,head): bf16 B-operand mats ([col][k], k contig):
//   mat0 = WK^T, mat1 = WV^T,
//   mat2..4 = WQE[et] with Qe = x @ (WQ @ WE[et]^T)
// ---------------------------------------------------------------------------
__global__ __launch_bounds__(256) void wprep_kernel(
    const float* __restrict__ W_Q, const float* __restrict__ W_K,
    const float* __restrict__ W_V, const float* __restrict__ W_E,
    u16* __restrict__ wqkvb) {
  int b = blockIdx.x;
  int h = b & 7, tt = (b >> 3) & 3, l = b >> 5;
  __shared__ float wq[1024];
  __shared__ float we[3][1024];
  int t = threadIdx.x;
  const float* WQp = W_Q + (((size_t)l * NTYPE + tt) * NHEAD + h) * 1024;
  for (int i = t; i < 1024; i += 256) wq[i] = WQp[i];
  for (int et = 0; et < ETYPE; ++et) {
    const float* WEp = W_E + (((size_t)l * ETYPE + et) * NHEAD + h) * 1024;
    for (int i = t; i < 1024; i += 256) we[et][i] = WEp[i];
  }
  __syncthreads();
  const float* WKp = W_K + (((size_t)l * NTYPE + tt) * NHEAD + h) * 1024;
  const float* WVp = W_V + (((size_t)l * NTYPE + tt) * NHEAD + h) * 1024;
  u16* out = wqkvb + (size_t)b * 5120;
  for (int i = t; i < 1024; i += 256) {
    int col = i >> 5, k = i & 31;
    out[i] = f2bf(WKp[k * 32 + col]);
    out[1024 + i] = f2bf(WVp[k * 32 + col]);
#pragma unroll
    for (int et = 0; et < ETYPE; ++et) {
      float a = 0.f;
#pragma unroll
      for (int j = 0; j < 32; ++j) a += wq[k * 32 + j] * we[et][col * 32 + j];
      out[(2 + et) * 1024 + i] = f2bf(a);
    }
  }
}

// ---------------------------------------------------------------------------
// QKV via MFMA over type buckets: K,V stored fp8 e4m3, Qe[3] bf16
// ---------------------------------------------------------------------------
__global__ __launch_bounds__(256) void qkv_mfma(
    const u16* __restrict__ xb, const int* __restrict__ tidx,
    const int* __restrict__ toff, const int* __restrict__ tile_off,
    const u16* __restrict__ wqkvb_l,
    u8* __restrict__ Kb8, u8* __restrict__ Vb8, u16* __restrict__ Qeb) {
  __shared__ u16 smem[10240];
  int bx = blockIdx.x, h = blockIdx.y;
  if (bx >= tile_off[NTYPE]) return;
  int ty = 0;
  while (bx >= tile_off[ty + 1]) ++ty;
  int lt = bx - tile_off[ty];
  int base = toff[ty] + lt * 64;
  int cnt = min(64, toff[ty + 1] - toff[ty] - lt * 64);
  int t = threadIdx.x;
  {
    int row = t >> 2, q = t & 3;
    int node = tidx[base + min(row, cnt - 1)];
    *(uint4*)&smem[row * 32 + q * 8] =
        *(const uint4*)&xb[(size_t)node * 256 + h * 32 + q * 8];
  }
  const u16* wsrc = wqkvb_l + ((size_t)ty * NHEAD + h) * 5120;
  for (int c = t; c < 640; c += 256)
    *(uint4*)&smem[2048 + c * 8] = *(const uint4*)&wsrc[c * 8];
  __syncthreads();

  int lane = t & 63, w = t >> 6;
  int m = lane & 15, q = lane >> 4;
  bf16x8 af = *(const bf16x8*)&smem[(w * 16 + m) * 32 + q * 8];
  f32x4 acc[5][2];
#pragma unroll
  for (int mt = 0; mt < 5; ++mt)
#pragma unroll
    for (int c = 0; c < 2; ++c) {
      bf16x8 bf = *(const bf16x8*)&smem[2048 + mt * 1024 + (c * 16 + m) * 32 + q * 8];
      acc[mt][c] = __builtin_amdgcn_mfma_f32_16x16x32_bf16(af, bf, (f32x4){0.f, 0.f, 0.f, 0.f}, 0, 0, 0);
    }
  __syncthreads();
#pragma unroll
  for (int mt = 0; mt < 5; ++mt)
#pragma unroll
    for (int c = 0; c < 2; ++c)
#pragma unroll
      for (int r = 0; r < 4; ++r)
        smem[mt * 2048 + (w * 16 + q * 4 + r) * 32 + c * 16 + m] = f2bf(acc[mt][c][r]);
  __syncthreads();
  {
    int row = t >> 2, q4 = t & 3;
    if (row < cnt) {
      int node = tidx[base + row];
      {
        const u16* sp = &smem[row * 32 + q4 * 8];
        unsigned long long pk = 0;
#pragma unroll
        for (int j = 0; j < 8; ++j)
          pk |= (unsigned long long)f2fp8(bf2f(sp[j])) << (8 * j);
        *(unsigned long long*)&Kb8[(size_t)node * 256 + h * 32 + q4 * 8] = pk;
      }
      {
        const u16* sp = &smem[2048 + row * 32 + q4 * 8];
        unsigned long long pk = 0;
#pragma unroll
        for (int j = 0; j < 8; ++j)
          pk |= (unsigned long long)f2fp8(bf2f(sp[j])) << (8 * j);
        *(unsigned long long*)&Vb8[(size_t)node * 256 + h * 32 + q4 * 8] = pk;
      }
#pragma unroll
      for (int et = 0; et < ETYPE; ++et)
        *(uint4*)&Qeb[((size_t)node * ETYPE + et) * 256 + h * 32 + q4 * 8] =
            *(const uint4*)&smem[(2 + et) * 2048 + row * 32 + q4 * 8];
    }
  }
}

// ---------------------------------------------------------------------------
// Edge scores -> exp(score). fp8 K gather (5 MB working set)
// ---------------------------------------------------------------------------
__global__ __launch_bounds__(256) void score_kernel(
    const int* __restrict__ csr_src, const int* __restrict__ csr_dst,
    const int* __restrict__ csr_et, const u16* __restrict__ Qeb,
    const u8* __restrict__ Kb8, const float* __restrict__ mu,
    float* __restrict__ scores, int E) {
  int tid = blockIdx.x * 256 + threadIdx.x;
  if (tid >= E * NHEAD) return;
  int p = tid >> 3, h = tid & 7;
  int s = csr_src[p], d = csr_dst[p], t = csr_et[p];
  const bf16x8* q = (const bf16x8*)(Qeb + ((size_t)d * ETYPE + t) * 256 + h * 32);
  const uint2* k = (const uint2*)(Kb8 + (size_t)s * 256 + h * 32);
  float acc = 0.f;
#pragma unroll
  for (int g = 0; g < 4; ++g) {
    uint2 kd = k[g];
    bf16x8 qq = q[g];
#pragma unroll
    for (int b = 0; b < 4; ++b) {
      acc += fp82f((kd.x >> (8 * b)) & 0xffu) * (float)qq[b];
      acc += fp82f((kd.y >> (8 * b)) & 0xffu) * (float)qq[4 + b];
    }
  }
  scores[tid] = __expf(acc * 0.17677669529663687f * mu[h * ETYPE + t]);
}

// ---------------------------------------------------------------------------
// Segment softmax + V aggregation with 4-WAY EDGE PARALLELISM: 4 groups of
// 64 threads each walk every 4th edge (4 independent gather chains in flight
// vs R10's serial 2-unroll — the kernel was latency-bound at 11% HBM / 26%
// VALU). Thread covers 4 dims via one uint (4xfp8) load; cross-group reduce
// through LDS once at the end.
// ---------------------------------------------------------------------------
__global__ __launch_bounds__(256) void agg_kernel(
    const int* __restrict__ off, const int* __restrict__ csr_src,
    const float* __restrict__ scores, const u8* __restrict__ Vb8,
    u16* __restrict__ aggb) {
  __shared__ float sacc[4][256];
  __shared__ float sssum[4][8];
  int n = blockIdx.x;
  int t = threadIdx.x;
  int g = t >> 6;          // edge group 0..3
  int l = t & 63;          // lane in group
  int d0 = l * 4;          // dims [d0, d0+4)
  int h = l >> 3;          // head of these dims
  int s0 = off[n], s1 = off[n + 1];
  float a0 = 0.f, a1 = 0.f, a2 = 0.f, a3 = 0.f, ssum = 0.f;
  for (int k = s0 + g; k < s1; k += 4) {
    int sn = csr_src[k];
    float e = scores[(size_t)k * 8 + h];
    unsigned v4 = *(const unsigned*)(Vb8 + (size_t)sn * 256 + d0);
    a0 += e * fp82f(v4 & 0xffu);
    a1 += e * fp82f((v4 >> 8) & 0xffu);
    a2 += e * fp82f((v4 >> 16) & 0xffu);
    a3 += e * fp82f((v4 >> 24) & 0xffu);
    ssum += e;
  }
  *(float4*)&sacc[g][d0] = make_float4(a0, a1, a2, a3);
  if ((l & 7) == 0) sssum[g][h] = ssum;
  __syncthreads();
  int hh = t >> 5;
  float tot = sacc[0][t] + sacc[1][t] + sacc[2][t] + sacc[3][t];
  float st = sssum[0][hh] + sssum[1][hh] + sssum[2][hh] + sssum[3][hh];
  aggb[(size_t)n * 256 + t] = f2bf(tot / (st + 1e-10f));
}

// ---------------------------------------------------------------------------
// fp32 [K,Nc] -> bf16 transposed [Nc,K]
// ---------------------------------------------------------------------------
__global__ __launch_bounds__(256) void convT_kernel(const float* __restrict__ W,
                                                    u16* __restrict__ Wt, int K, int Nc) {
  __shared__ float tile[32][33];
  int bk = blockIdx.y * 32, bn = blockIdx.x * 32;
  const float* Wz = W + (size_t)blockIdx.z * K * Nc;
  u16* Wtz = Wt + (size_t)blockIdx.z * K * Nc;
  int tx = threadIdx.x & 31, ty = threadIdx.x >> 5;
  for (int r = ty; r < 32; r += 8)
    tile[r][tx] = Wz[(size_t)(bk + r) * Nc + bn + tx];
  __syncthreads();
  for (int r = ty; r < 32; r += 8)
    Wtz[(size_t)(bn + r) * K + bk + tx] = f2bf(tile[tx][r]);
}

// ---------------------------------------------------------------------------
// bf16 MFMA GEMM: C[M,Nc] = A[M,K] @ Bt[Nc,K]^T + bias -> bf16 out.
// BM=128, BN template (64 for Nc=256 outputs: grid >600 blocks).
// GELU=1 adds fast-GELU to the epilogue.
// ---------------------------------------------------------------------------
template <int GELU, int BN>
__global__ __launch_bounds__(256) void gemm_mfma(
    const u16* __restrict__ A, const u16* __restrict__ Bt,
    const float* __restrict__ bias, u16* __restrict__ Cb,
    int M, int K, int Nc) {
  __shared__ u16 As[128 * 32];
  __shared__ u16 Bs[BN * 32];
  const int MJ = BN / 32;
  const int t = threadIdx.x;
  const int lane = t & 63;
  const int w = t >> 6;
  const int row0 = blockIdx.y * 128;
  const int col0 = blockIdx.x * BN;
  const int wm = (w >> 1) * 64, wn = (w & 1) * (BN / 2);

  f32x4 acc[4][4] = {};
  const int sr = lane >> 2;
  const int sk = (lane & 3) * 8;

  for (int k0 = 0; k0 < K; k0 += 32) {
#pragma unroll
    for (int c = 0; c < 2; ++c) {
      const int chunk = w * 2 + c;
      const int r = chunk * 16 + sr;
      int ra = row0 + r; if (ra >= M) ra = M - 1;
      GLDS16(A + (size_t)ra * K + k0 + sk, &As[(chunk * 64 + lane) * 8]);
      if (BN == 128) {
        GLDS16(Bt + (size_t)(col0 + r) * K + k0 + sk, &Bs[(chunk * 64 + lane) * 8]);
      }
    }
    if (BN == 64) {
      const int r = w * 16 + sr;
      GLDS16(Bt + (size_t)(col0 + r) * K + k0 + sk, &Bs[(w * 64 + lane) * 8]);
    }
    __syncthreads();
    bf16x8 af[4], bfr[4];
    const int ko = (lane >> 4) * 8;
    const int lr = lane & 15;
#pragma unroll
    for (int i = 0; i < 4; ++i)
      af[i] = *(const bf16x8*)&As[(wm + i * 16 + lr) * 32 + ko];
#pragma unroll
    for (int j = 0; j < MJ; ++j)
      bfr[j] = *(const bf16x8*)&Bs[(wn + j * 16 + lr) * 32 + ko];
#pragma unroll
    for (int i = 0; i < 4; ++i)
#pragma unroll
      for (int j = 0; j < MJ; ++j)
        acc[i][j] = __builtin_amdgcn_mfma_f32_16x16x32_bf16(af[i], bfr[j], acc[i][j], 0, 0, 0);
    __syncthreads();
  }

  const int lc = lane & 15;
  const int lrow = (lane >> 4) * 4;
#pragma unroll
  for (int i = 0; i < 4; ++i) {
#pragma unroll
    for (int r = 0; r < 4; ++r) {
      int gr = row0 + wm + i * 16 + lrow + r;
      if (gr >= M) continue;
#pragma unroll
      for (int j = 0; j < MJ; ++j) {
        int gc = col0 + wn + j * 16 + lc;
        float v = acc[i][j][r] + bias[gc];
        if (GELU) v = gelu_f(v);
        Cb[(size_t)gr * Nc + gc] = f2bf(v);
      }
    }
  }
}

// ---------------------------------------------------------------------------
// LayerNorm rows of 256: out = LN(xin + res) * g + b; res is bf16 (or null).
// xbuf stays the fp32 residual master.
// ---------------------------------------------------------------------------
__global__ __launch_bounds__(256) void ln_kernel(
    const float* __restrict__ xin, const u16* __restrict__ res,
    const float* __restrict__ g, const float* __restrict__ b,
    float* __restrict__ out, u16* __restrict__ outb) {
  int n = blockIdx.x;
  int t = threadIdx.x;
  __shared__ float red[8];
  size_t idx = (size_t)n * 256 + t;
  float r = xin[idx] + (res ? bf2f(res[idx]) : 0.f);
  float s = r;
  for (int o = 32; o > 0; o >>= 1) s += __shfl_xor(s, o, 64);
  if ((t & 63) == 0) red[t >> 6] = s;
  __syncthreads();
  float m = (red[0] + red[1] + red[2] + red[3]) * (1.f / 256.f);
  float d = r - m;
  float s2 = d * d;
  for (int o = 32; o > 0; o >>= 1) s2 += __shfl_xor(s2, o, 64);
  if ((t & 63) == 0) red[4 + (t >> 6)] = s2;
  __syncthreads();
  float var = (red[4] + red[5] + red[6] + red[7]) * (1.f / 256.f);
  float o = d * rsqrtf(var + 1e-5f) * g[t] + b[t];
  out[idx] = o;
  if (outb) outb[idx] = f2bf(o);
}

// ---------------------------------------------------------------------------
extern "C" void kernel_launch(void* const* d_in, const int* in_sizes, int n_in,
                              void* d_out, int out_size, void* d_ws, size_t ws_size,
                              hipStream_t stream) {
  const float* x_in   = (const float*)d_in[0];
  const int*   ei     = (const int*)d_in[1];
  const int*   etype  = (const int*)d_in[2];
  const int*   ntype  = (const int*)d_in[3];
  const float* W_Q    = (const float*)d_in[4];
  const float* W_K    = (const float*)d_in[5];
  const float* W_V    = (const float*)d_in[6];
  const float* W_E    = (const float*)d_in[7];
  const float* mu     = (const float*)d_in[8];
  const float* Wo     = (const float*)d_in[9];
  const float* bo     = (const float*)d_in[10];
  const float* ln1g   = (const float*)d_in[11];
  const float* ln1b   = (const float*)d_in[12];
  const float* ln2g   = (const float*)d_in[13];
  const float* ln2b   = (const float*)d_in[14];
  const float* w1     = (const float*)d_in[15];
  const float* b1     = (const float*)d_in[16];
  const float* w2     = (const float*)d_in[17];
  const float* b2     = (const float*)d_in[18];
  const float* outg   = (const float*)d_in[19];
  const float* outb   = (const float*)d_in[20];

  const int N = in_sizes[0] / DMODEL;    // 20000
  const int E = in_sizes[1] / 2;         // 320000
  const int* src = ei;
  const int* dst = ei + E;

  const size_t NF = (size_t)N * DMODEL;
  const size_t EH = (size_t)E * NHEAD;

  // ---- workspace layout ----
  float* f      = (float*)d_ws;
  float* xbuf   = f;                     // NF fp32 (residual master)
  float* scores = f + NF;                // EH fp32 (holds exp(score))
  u16*   fout   = (u16*)(f + NF + EH);   // NF bf16 (GEMM outputs)
  u16*   xb     = fout + NF;             // NF bf16
  u16*   Qeb    = xb + NF;               // 3NF bf16  } h1b aliases Qeb
  u16*   h1b    = Qeb;                   // alias (2NF used, FFN phase only)
  u16*   aggb   = Qeb + 3 * NF;          // NF bf16
  u8*    Kb8    = (u8*)(aggb + NF);      // NF bytes fp8
  u8*    Vb8    = Kb8 + NF;              // NF bytes fp8
  u16*   wqkvb  = (u16*)(Vb8 + NF);      // 96 * 5120
  u16*   Wot    = wqkvb + (size_t)NLAYER * NTYPE * NHEAD * 5120;
  u16*   w1t    = Wot + 3 * 65536;
  u16*   w2t    = w1t + 3 * 262144;
  int*   ip     = (int*)(w2t + 3 * 262144);
  int*   off    = ip;                    // N+1
  int*   csr_src= off + (N + 1);         // E
  int*   csr_dst= csr_src + E;           // E
  int*   csr_et = csr_dst + E;           // E
  int*   cursor = csr_et + E;            // N
  int*   tidx   = cursor + N;            // N
  int*   toff   = tidx + N;              // NTYPE+1
  int*   tile_off = toff + (NTYPE + 1);  // NTYPE+1
  int*   tcnt   = tile_off + (NTYPE + 1);// NTYPE
  int*   tcur   = tcnt + NTYPE;          // NTYPE

  // ---- CSR + type buckets (once) ----
  hipMemsetAsync(cursor, 0, (size_t)N * sizeof(int), stream);
  hipMemsetAsync(tcnt, 0, 2 * NTYPE * sizeof(int), stream);
  count_deg_kernel<<<(E + 255) / 256, 256, 0, stream>>>(dst, cursor, E);
  scan_kernel<<<1, 1024, 0, stream>>>(cursor, off, N);
  hipMemsetAsync(cursor, 0, (size_t)N * sizeof(int), stream);
  scatter_kernel<<<(E + 255) / 256, 256, 0, stream>>>(
      src, dst, etype, off, cursor, csr_src, csr_dst, csr_et, E);
  tcount_kernel<<<(N + 255) / 256, 256, 0, stream>>>(ntype, tcnt, N);
  tscan_kernel<<<1, 64, 0, stream>>>(tcnt, toff, tile_off);
  tscatter_kernel<<<(N + 255) / 256, 256, 0, stream>>>(ntype, toff, tcur, tidx, N);

  // ---- weight prep (once) ----
  wprep_kernel<<<NLAYER * NTYPE * NHEAD, 256, 0, stream>>>(W_Q, W_K, W_V, W_E, wqkvb);
  convT_kernel<<<dim3(DMODEL / 32, DMODEL / 32, NLAYER), 256, 0, stream>>>(
      Wo, Wot, DMODEL, DMODEL);
  convT_kernel<<<dim3(4 * DMODEL / 32, DMODEL / 32, NLAYER), 256, 0, stream>>>(
      w1, w1t, DMODEL, 4 * DMODEL);
  convT_kernel<<<dim3(DMODEL / 32, 4 * DMODEL / 32, NLAYER), 256, 0, stream>>>(
      w2, w2t, 4 * DMODEL, DMODEL);

  // ---- x working copies ----
  hipMemcpyAsync(xbuf, x_in, NF * sizeof(float), hipMemcpyDeviceToDevice, stream);
  xconv_kernel<<<(int)((NF / 4 + 255) / 256), 256, 0, stream>>>(x_in, xb, (int)(NF / 4));

  const int gm = (N + 127) / 128;
  const int qtiles = (N + 63) / 64 + NTYPE;
  for (int l = 0; l < NLAYER; ++l) {
    qkv_mfma<<<dim3(qtiles, NHEAD), 256, 0, stream>>>(
        xb, tidx, toff, tile_off,
        wqkvb + (size_t)l * NTYPE * NHEAD * 5120, Kb8, Vb8, Qeb);
    score_kernel<<<(int)((EH + 255) / 256), 256, 0, stream>>>(
        csr_src, csr_dst, csr_et, Qeb, Kb8, mu + (size_t)l * NHEAD * ETYPE, scores, E);
    agg_kernel<<<N, 256, 0, stream>>>(off, csr_src, scores, Vb8, aggb);

    gemm_mfma<0, 64><<<dim3(DMODEL / 64, gm), 256, 0, stream>>>(
        aggb, Wot + (size_t)l * 65536, bo + (size_t)l * DMODEL,
        fout, N, DMODEL, DMODEL);
    ln_kernel<<<N, 256, 0, stream>>>(xbuf, fout,
        ln1g + (size_t)l * DMODEL, ln1b + (size_t)l * DMODEL, xbuf, xb);
    gemm_mfma<1, 128><<<dim3(4 * DMODEL / 128, gm), 256, 0, stream>>>(
        xb, w1t + (size_t)l * 262144, b1 + (size_t)l * 4 * DMODEL,
        h1b, N, DMODEL, 4 * DMODEL);
    gemm_mfma<0, 64><<<dim3(DMODEL / 64, gm), 256, 0, stream>>>(
        h1b, w2t + (size_t)l * 262144, b2 + (size_t)l * DMODEL,
        fout, N, 4 * DMODEL, DMODEL);
    ln_kernel<<<N, 256, 0, stream>>>(xbuf, fout,
        ln2g + (size_t)l * DMODEL, ln2b + (size_t)l * DMODEL, xbuf, xb);
  }

  ln_kernel<<<N, 256, 0, stream>>>(xbuf, nullptr, outg, outb, (float*)d_out, nullptr);
}